// Round 1
// baseline (383.629 us; speedup 1.0000x reference)
//
#include <hip/hip_runtime.h>

#define B_TOK 2048
#define W_DIM 512
#define E_N 16
#define INTER 1024
#define SH_INTER 2048
#define OUT_DIM 128

#define BM 64
#define BN 64
#define BK 32

typedef unsigned short u16;
typedef __attribute__((ext_vector_type(8))) short bf16x8;
typedef __attribute__((ext_vector_type(4))) float f32x4;

__device__ __forceinline__ u16 f2b(float f) {
    union { float f; unsigned u; } x; x.f = f;
    unsigned r = x.u + 0x7FFFu + ((x.u >> 16) & 1u);
    return (u16)(r >> 16);
}

__device__ __forceinline__ void gld16(const void* g, void* l) {
    __builtin_amdgcn_global_load_lds(
        (const __attribute__((address_space(1))) void*)g,
        (__attribute__((address_space(3))) void*)l, 16, 0, 0);
}

// ---------------- cast fp32 -> bf16, 4 elems/thread ----------------
__global__ __launch_bounds__(256)
void cast_bf16(const float4* __restrict__ in, ushort4* __restrict__ out, int n4) {
    int i = blockIdx.x * 256 + threadIdx.x;
    if (i < n4) {
        float4 v = in[i];
        ushort4 o;
        o.x = f2b(v.x); o.y = f2b(v.y); o.z = f2b(v.z); o.w = f2b(v.w);
        out[i] = o;
    }
}

// ---------------- init: zero meta[0..63] ----------------
__global__ void init_meta(int* meta) {
    if (threadIdx.x < 64) meta[threadIdx.x] = 0;
}

// ---------------- gate: fp32 logits, softmax, top-2 ----------------
// meta: [0..15]=counts [16..31]=cursor [32..47]=offs [48]=0 [49]=B
__global__ __launch_bounds__(256)
void gate_topk(const float* __restrict__ x, const float* __restrict__ gw,
               int* __restrict__ topi, float* __restrict__ topw, int* __restrict__ meta) {
    const int lane = threadIdx.x & 63;
    const int wv   = threadIdx.x >> 6;
    const int t    = blockIdx.x * 4 + wv;
    const int e = lane >> 2, q = lane & 3;
    const float* xr = x + (size_t)t * W_DIM;
    const float* wr = gw + (size_t)e * W_DIM;
    float s = 0.f;
    for (int wi = q; wi < W_DIM; wi += 4) s += xr[wi] * wr[wi];
    s += __shfl_xor(s, 1);
    s += __shfl_xor(s, 2);
    float sc[16];
    #pragma unroll
    for (int ee = 0; ee < 16; ++ee) sc[ee] = __shfl(s, ee * 4);
    float mx = sc[0];
    #pragma unroll
    for (int ee = 1; ee < 16; ++ee) mx = fmaxf(mx, sc[ee]);
    float p[16]; float sum = 0.f;
    #pragma unroll
    for (int ee = 0; ee < 16; ++ee) { p[ee] = expf(sc[ee] - mx); sum += p[ee]; }
    const float inv = 1.f / sum;
    int i0 = 0; float v0 = sc[0];
    #pragma unroll
    for (int ee = 1; ee < 16; ++ee) if (sc[ee] > v0) { v0 = sc[ee]; i0 = ee; }
    int i1 = -1; float v1 = -1e30f;
    #pragma unroll
    for (int ee = 0; ee < 16; ++ee) if (ee != i0 && sc[ee] > v1) { v1 = sc[ee]; i1 = ee; }
    if (lane == 0) {
        topi[t * 2 + 0] = i0; topi[t * 2 + 1] = i1;
        topw[t * 2 + 0] = p[i0] * inv; topw[t * 2 + 1] = p[i1] * inv;
        atomicAdd(&meta[i0], 1); atomicAdd(&meta[i1], 1);
    }
}

// ---------------- exclusive scan over 16 counts ----------------
__global__ void scan_offs(int* meta) {
    if (threadIdx.x == 0) {
        int acc = 0;
        for (int e = 0; e < 16; ++e) { meta[32 + e] = acc; acc += meta[e]; meta[16 + e] = 0; }
        meta[48] = 0; meta[49] = B_TOK;
    }
}

// ---------------- scatter tokens to per-expert job lists ----------------
__global__ __launch_bounds__(256)
void scatter_jobs(const int* __restrict__ topi, const float* __restrict__ topw,
                  int* __restrict__ meta, int* __restrict__ job_tok,
                  float* __restrict__ job_w, int* __restrict__ t2r, int* __restrict__ ident) {
    int t = blockIdx.x * 256 + threadIdx.x;
    if (t >= B_TOK) return;
    ident[t] = t;
    for (int k = 0; k < 2; ++k) {
        int e = topi[t * 2 + k];
        int pos = atomicAdd(&meta[16 + e], 1);
        int row = meta[32 + e] + pos;
        job_tok[row] = t;
        job_w[row] = topw[t * 2 + k];
        t2r[t * 2 + k] = row;
    }
}

// ---------------- G1: dual GEMM + leaky*mul, bf16 out ----------------
// A: bf16 [*,K] gathered by glist[base+row]. B1w/B3w: [E][N][K]. Hout rows base+gm, ld N.
__global__ __launch_bounds__(256)
void g1_dual(const u16* __restrict__ A, const int* __restrict__ glist,
             const int* __restrict__ offs, const int* __restrict__ cnt,
             const u16* __restrict__ B1w, const u16* __restrict__ B3w,
             const float* __restrict__ bias1, const float* __restrict__ bias3,
             u16* __restrict__ Hout, int N, int K) {
    const int e = blockIdx.z;
    const int base = offs[e];
    const int Me = cnt[e];
    const int m0 = blockIdx.x * BM;
    if (m0 >= Me) return;
    const int n0 = blockIdx.y * BN;

    __shared__ __align__(16) u16 sA[BM * BK];
    __shared__ __align__(16) u16 sB1[BN * BK];
    __shared__ __align__(16) u16 sB3[BN * BK];

    const int tid = threadIdx.x;
    const int lane = tid & 63;
    const int wv = tid >> 6;
    const int srow = wv * 16 + (lane >> 2);
    const int kq = (lane & 3) * 8;

    const int arow = m0 + srow;
    const int tokA = glist[base + (arow < Me ? arow : 0)];
    const u16* gA = A + (size_t)tokA * K + kq;
    const size_t bO = (size_t)e * N * K + (size_t)(n0 + srow) * K + kq;
    const u16* gB1 = B1w + bO;
    const u16* gB3 = B3w + bO;
    u16* lA = &sA[srow * BK + kq];
    u16* lB1 = &sB1[srow * BK + kq];
    u16* lB3 = &sB3[srow * BK + kq];

    const int wm = wv >> 1, wn = wv & 1;
    const int l15 = lane & 15, lhi = lane >> 4;

    f32x4 acc1[2][2] = {};
    f32x4 acc3[2][2] = {};

    for (int k0 = 0; k0 < K; k0 += BK) {
        gld16(gA + k0, lA);
        gld16(gB1 + k0, lB1);
        gld16(gB3 + k0, lB3);
        __syncthreads();
        bf16x8 af[2], bf1[2], bf3[2];
        #pragma unroll
        for (int i = 0; i < 2; ++i)
            af[i] = *(const bf16x8*)&sA[(wm * 32 + i * 16 + l15) * BK + lhi * 8];
        #pragma unroll
        for (int j = 0; j < 2; ++j) {
            bf1[j] = *(const bf16x8*)&sB1[(wn * 32 + j * 16 + l15) * BK + lhi * 8];
            bf3[j] = *(const bf16x8*)&sB3[(wn * 32 + j * 16 + l15) * BK + lhi * 8];
        }
        #pragma unroll
        for (int i = 0; i < 2; ++i)
            #pragma unroll
            for (int j = 0; j < 2; ++j) {
                acc1[i][j] = __builtin_amdgcn_mfma_f32_16x16x32_bf16(af[i], bf1[j], acc1[i][j], 0, 0, 0);
                acc3[i][j] = __builtin_amdgcn_mfma_f32_16x16x32_bf16(af[i], bf3[j], acc3[i][j], 0, 0, 0);
            }
        __syncthreads();
    }

    #pragma unroll
    for (int i = 0; i < 2; ++i)
    #pragma unroll
    for (int j = 0; j < 2; ++j) {
        const int col = n0 + wn * 32 + j * 16 + l15;
        const float bb1 = bias1[(size_t)e * N + col];
        const float bb3 = bias3[(size_t)e * N + col];
        #pragma unroll
        for (int r = 0; r < 4; ++r) {
            const int gm = m0 + wm * 32 + i * 16 + lhi * 4 + r;
            if (gm < Me) {
                float v1 = acc1[i][j][r] + bb1;
                float v3 = acc3[i][j][r] + bb3;
                v1 = v1 >= 0.f ? v1 : 0.01f * v1;
                Hout[(size_t)(base + gm) * N + col] = f2b(v1 * v3);
            }
        }
    }
}

// ---------------- G2: GEMM + bias (+ per-row scale), fp32 out ----------------
// A rows are base+row (contiguous). Bw: [E][N][K]. Out rows base+gm, ld N.
__global__ __launch_bounds__(256)
void g2_gemm(const u16* __restrict__ A, const int* __restrict__ offs,
             const int* __restrict__ cnt, const u16* __restrict__ Bw,
             const float* __restrict__ bias, const float* __restrict__ scale,
             float* __restrict__ Out, int N, int K) {
    const int e = blockIdx.z;
    const int base = offs[e];
    const int Me = cnt[e];
    const int m0 = blockIdx.x * BM;
    if (m0 >= Me) return;
    const int n0 = blockIdx.y * BN;

    __shared__ __align__(16) u16 sA[BM * BK];
    __shared__ __align__(16) u16 sB[BN * BK];

    const int tid = threadIdx.x;
    const int lane = tid & 63;
    const int wv = tid >> 6;
    const int srow = wv * 16 + (lane >> 2);
    const int kq = (lane & 3) * 8;

    const int arow = m0 + srow;
    const u16* gA = A + (size_t)(base + (arow < Me ? arow : 0)) * K + kq;
    const u16* gB = Bw + (size_t)e * N * K + (size_t)(n0 + srow) * K + kq;
    u16* lA = &sA[srow * BK + kq];
    u16* lB = &sB[srow * BK + kq];

    const int wm = wv >> 1, wn = wv & 1;
    const int l15 = lane & 15, lhi = lane >> 4;

    f32x4 acc[2][2] = {};

    for (int k0 = 0; k0 < K; k0 += BK) {
        gld16(gA + k0, lA);
        gld16(gB + k0, lB);
        __syncthreads();
        bf16x8 af[2], bf[2];
        #pragma unroll
        for (int i = 0; i < 2; ++i)
            af[i] = *(const bf16x8*)&sA[(wm * 32 + i * 16 + l15) * BK + lhi * 8];
        #pragma unroll
        for (int j = 0; j < 2; ++j)
            bf[j] = *(const bf16x8*)&sB[(wn * 32 + j * 16 + l15) * BK + lhi * 8];
        #pragma unroll
        for (int i = 0; i < 2; ++i)
            #pragma unroll
            for (int j = 0; j < 2; ++j)
                acc[i][j] = __builtin_amdgcn_mfma_f32_16x16x32_bf16(af[i], bf[j], acc[i][j], 0, 0, 0);
        __syncthreads();
    }

    #pragma unroll
    for (int i = 0; i < 2; ++i)
    #pragma unroll
    for (int j = 0; j < 2; ++j) {
        const int col = n0 + wn * 32 + j * 16 + l15;
        const float bb = bias[(size_t)e * N + col];
        #pragma unroll
        for (int r = 0; r < 4; ++r) {
            const int gm = m0 + wm * 32 + i * 16 + lhi * 4 + r;
            if (gm < Me) {
                float v = acc[i][j][r] + bb;
                if (scale) v *= scale[base + gm];
                Out[(size_t)(base + gm) * N + col] = v;
            }
        }
    }
}

// ---------------- combine: ybf = bf16(y2[r0] + y2[r1] + z) ----------------
__global__ __launch_bounds__(256)
void combine_k(const float* __restrict__ y2, const float* __restrict__ z,
               const int* __restrict__ t2r, u16* __restrict__ ybf) {
    int idx = blockIdx.x * 256 + threadIdx.x;   // [0, B*W/4)
    int t = idx >> 7;
    int w4 = (idx & 127) << 2;
    int r0 = t2r[t * 2 + 0], r1 = t2r[t * 2 + 1];
    const float4 a = *(const float4*)(y2 + (size_t)r0 * W_DIM + w4);
    const float4 b = *(const float4*)(y2 + (size_t)r1 * W_DIM + w4);
    const float4 c = *(const float4*)(z + (size_t)t * W_DIM + w4);
    ushort4 o;
    o.x = f2b(a.x + b.x + c.x);
    o.y = f2b(a.y + b.y + c.y);
    o.z = f2b(a.z + b.z + c.z);
    o.w = f2b(a.w + b.w + c.w);
    *(ushort4*)(ybf + (size_t)t * W_DIM + w4) = o;
}

extern "C" void kernel_launch(void* const* d_in, const int* in_sizes, int n_in,
                              void* d_out, int out_size, void* d_ws, size_t ws_size,
                              hipStream_t stream) {
    const float* x      = (const float*)d_in[0];
    const float* gate_w = (const float*)d_in[2];
    const float* w1     = (const float*)d_in[3];
    const float* b1     = (const float*)d_in[4];
    const float* w2     = (const float*)d_in[5];
    const float* b2     = (const float*)d_in[6];
    const float* w3     = (const float*)d_in[7];
    const float* b3     = (const float*)d_in[8];
    const float* sw1    = (const float*)d_in[9];
    const float* sb1    = (const float*)d_in[10];
    const float* sw2    = (const float*)d_in[11];
    const float* sb2    = (const float*)d_in[12];
    const float* sw3    = (const float*)d_in[13];
    const float* sb3    = (const float*)d_in[14];
    const float* ow     = (const float*)d_in[15];
    const float* ob     = (const float*)d_in[16];
    float* out = (float*)d_out;

    char* ws = (char*)d_ws;
    size_t off = 0;
    auto alloc = [&](size_t bytes) -> void* {
        void* p = (void*)(ws + off);
        off += (bytes + 255) & ~(size_t)255;
        return p;
    };

    int*   meta    = (int*)alloc(256);
    int*   topi    = (int*)alloc((size_t)B_TOK * 2 * 4);
    float* topw    = (float*)alloc((size_t)B_TOK * 2 * 4);
    int*   t2r     = (int*)alloc((size_t)B_TOK * 2 * 4);
    int*   job_tok = (int*)alloc((size_t)B_TOK * 2 * 4);
    float* job_w   = (float*)alloc((size_t)B_TOK * 2 * 4);
    int*   ident   = (int*)alloc((size_t)B_TOK * 4);
    u16*   xb      = (u16*)alloc((size_t)B_TOK * W_DIM * 2);
    u16*   w1b     = (u16*)alloc((size_t)E_N * INTER * W_DIM * 2);
    u16*   w3b     = (u16*)alloc((size_t)E_N * INTER * W_DIM * 2);
    u16*   w2b     = (u16*)alloc((size_t)E_N * W_DIM * INTER * 2);
    u16*   sw1b    = (u16*)alloc((size_t)SH_INTER * W_DIM * 2);
    u16*   sw3b    = (u16*)alloc((size_t)SH_INTER * W_DIM * 2);
    u16*   sw2b    = (u16*)alloc((size_t)W_DIM * SH_INTER * 2);
    u16*   owb     = (u16*)alloc((size_t)OUT_DIM * W_DIM * 2);
    u16*   hbuf    = (u16*)alloc((size_t)B_TOK * 2 * INTER * 2);
    u16*   pbuf    = (u16*)alloc((size_t)B_TOK * SH_INTER * 2);
    float* y2      = (float*)alloc((size_t)B_TOK * 2 * W_DIM * 4);
    float* zbuf    = (float*)alloc((size_t)B_TOK * W_DIM * 4);
    u16*   ybf     = (u16*)alloc((size_t)B_TOK * W_DIM * 2);
    if (off > ws_size) return;  // ws too small -> output stays zero (diagnostic)

    dim3 blk(256);

    init_meta<<<1, 64, 0, stream>>>(meta);

    auto cast = [&](const float* src, u16* dst, size_t n) {
        int n4 = (int)(n >> 2);
        cast_bf16<<<dim3((n4 + 255) / 256), blk, 0, stream>>>((const float4*)src, (ushort4*)dst, n4);
    };
    cast(x,   xb,   (size_t)B_TOK * W_DIM);
    cast(w1,  w1b,  (size_t)E_N * INTER * W_DIM);
    cast(w3,  w3b,  (size_t)E_N * INTER * W_DIM);
    cast(w2,  w2b,  (size_t)E_N * W_DIM * INTER);
    cast(sw1, sw1b, (size_t)SH_INTER * W_DIM);
    cast(sw3, sw3b, (size_t)SH_INTER * W_DIM);
    cast(sw2, sw2b, (size_t)W_DIM * SH_INTER);
    cast(ow,  owb,  (size_t)OUT_DIM * W_DIM);

    gate_topk<<<dim3(B_TOK / 4), blk, 0, stream>>>(x, gate_w, topi, topw, meta);
    scan_offs<<<1, 64, 0, stream>>>(meta);
    scatter_jobs<<<dim3(B_TOK / 256), blk, 0, stream>>>(topi, topw, meta, job_tok, job_w, t2r, ident);

    // routed h = leaky(x w1^T + b1) * (x w3^T + b3)   [jobs x INTER]
    g1_dual<<<dim3(B_TOK / BM, INTER / BN, E_N), blk, 0, stream>>>(
        xb, job_tok, meta + 32, meta, w1b, w3b, b1, b3, hbuf, INTER, W_DIM);
    // shared p = leaky(x sw1^T + sb1) * (x sw3^T + sb3)   [B x SH_INTER]
    g1_dual<<<dim3(B_TOK / BM, SH_INTER / BN, 1), blk, 0, stream>>>(
        xb, ident, meta + 48, meta + 49, sw1b, sw3b, sb1, sb3, pbuf, SH_INTER, W_DIM);
    // routed y2 = topw * (h w2^T + b2)   [jobs x W]
    g2_gemm<<<dim3(B_TOK / BM, W_DIM / BN, E_N), blk, 0, stream>>>(
        hbuf, meta + 32, meta, w2b, b2, job_w, y2, W_DIM, INTER);
    // shared z = p sw2^T + sb2   [B x W]
    g2_gemm<<<dim3(B_TOK / BM, W_DIM / BN, 1), blk, 0, stream>>>(
        pbuf, meta + 48, meta + 49, sw2b, sb2, nullptr, zbuf, W_DIM, SH_INTER);

    combine_k<<<dim3(B_TOK * W_DIM / 4 / 256), blk, 0, stream>>>(y2, zbuf, t2r, ybf);

    // out = (y+z) ow^T + ob   [B x OUT]
    g2_gemm<<<dim3(B_TOK / BM, OUT_DIM / BN, 1), blk, 0, stream>>>(
        ybf, meta + 48, meta + 49, owb, ob, nullptr, out, OUT_DIM, W_DIM);
}

// Round 2
// 192.681 us; speedup vs baseline: 1.9910x; 1.9910x over previous
//
#include <hip/hip_runtime.h>

#define B_TOK 2048
#define W_DIM 512
#define E_N 16
#define INTER 1024
#define SH_INTER 2048
#define OUT_DIM 128

typedef unsigned short u16;
typedef __attribute__((ext_vector_type(8))) short bf16x8;
typedef __attribute__((ext_vector_type(4))) float f32x4;

__device__ __forceinline__ u16 f2b(float f) {
    union { float f; unsigned u; } x; x.f = f;
    unsigned r = x.u + 0x7FFFu + ((x.u >> 16) & 1u);
    return (u16)(r >> 16);
}

__device__ __forceinline__ void gld16(const void* g, void* l) {
    __builtin_amdgcn_global_load_lds(
        (const __attribute__((address_space(1))) void*)g,
        (__attribute__((address_space(3))) void*)l, 16, 0, 0);
}

// meta layout (ints):
// [0..15] counts  [16..31] cursor  [32..47] offs
// [50] n_j1  [51] n_j2
// [64..127] j1e  [128..191] j1m   (g1 jobs, BM=128)
// [192..303] j2e [304..415] j2m   (g2 jobs, BM=64)

// ---------------- fused cast fp32->bf16 over 8 segments + meta init ----------------
struct CastSeg { const float4* src; ushort4* dst; int n4; };
struct CastArgs { CastSeg s[8]; int total4; int* meta; };

__global__ __launch_bounds__(256)
void cast_all(CastArgs a) {
    if (blockIdx.x == 0 && threadIdx.x < 64) a.meta[threadIdx.x] = 0;
    for (int i = blockIdx.x * 256 + threadIdx.x; i < a.total4; i += gridDim.x * 256) {
        int r = i, s = 0;
        while (r >= a.s[s].n4) { r -= a.s[s].n4; ++s; }
        float4 v = a.s[s].src[r];
        ushort4 o;
        o.x = f2b(v.x); o.y = f2b(v.y); o.z = f2b(v.z); o.w = f2b(v.w);
        a.s[s].dst[r] = o;
    }
}

// ---------------- gate: fp32 logits, softmax, top-2 ----------------
__global__ __launch_bounds__(256)
void gate_topk(const float* __restrict__ x, const float* __restrict__ gw,
               int* __restrict__ topi, float* __restrict__ topw, int* __restrict__ meta) {
    const int lane = threadIdx.x & 63;
    const int wv   = threadIdx.x >> 6;
    const int t    = blockIdx.x * 4 + wv;
    const int e = lane >> 2, q = lane & 3;
    const float4* xr = (const float4*)(x + (size_t)t * W_DIM);
    const float4* wr = (const float4*)(gw + (size_t)e * W_DIM);
    float s = 0.f;
    #pragma unroll
    for (int i = 0; i < W_DIM / 16; ++i) {
        float4 a = xr[q + 4 * i];
        float4 b = wr[q + 4 * i];
        s += a.x * b.x + a.y * b.y + a.z * b.z + a.w * b.w;
    }
    s += __shfl_xor(s, 1);
    s += __shfl_xor(s, 2);
    float sc[16];
    #pragma unroll
    for (int ee = 0; ee < 16; ++ee) sc[ee] = __shfl(s, ee * 4);
    float mx = sc[0];
    #pragma unroll
    for (int ee = 1; ee < 16; ++ee) mx = fmaxf(mx, sc[ee]);
    float p[16]; float sum = 0.f;
    #pragma unroll
    for (int ee = 0; ee < 16; ++ee) { p[ee] = expf(sc[ee] - mx); sum += p[ee]; }
    const float inv = 1.f / sum;
    int i0 = 0; float v0 = sc[0];
    #pragma unroll
    for (int ee = 1; ee < 16; ++ee) if (sc[ee] > v0) { v0 = sc[ee]; i0 = ee; }
    int i1 = -1; float v1 = -1e30f;
    #pragma unroll
    for (int ee = 0; ee < 16; ++ee) if (ee != i0 && sc[ee] > v1) { v1 = sc[ee]; i1 = ee; }
    if (lane == 0) {
        topi[t * 2 + 0] = i0; topi[t * 2 + 1] = i1;
        topw[t * 2 + 0] = p[i0] * inv; topw[t * 2 + 1] = p[i1] * inv;
        atomicAdd(&meta[i0], 1); atomicAdd(&meta[i1], 1);
    }
}

// ---------------- scan + build compact tile-job lists ----------------
__global__ void build_jobs(int* meta) {
    if (threadIdx.x != 0) return;
    int acc = 0;
    for (int e = 0; e < 16; ++e) { meta[32 + e] = acc; acc += meta[e]; meta[16 + e] = 0; }
    int jc = 0;
    for (int e = 0; e < 16; ++e)
        for (int m = 0; m < meta[e]; m += 128) { meta[64 + jc] = e; meta[128 + jc] = m; ++jc; }
    for (int m = 0; m < B_TOK; m += 128) { meta[64 + jc] = 16; meta[128 + jc] = m; ++jc; }
    meta[50] = jc;
    jc = 0;
    for (int e = 0; e < 16; ++e)
        for (int m = 0; m < meta[e]; m += 64) { meta[192 + jc] = e; meta[304 + jc] = m; ++jc; }
    for (int m = 0; m < B_TOK; m += 64) { meta[192 + jc] = 16; meta[304 + jc] = m; ++jc; }
    meta[51] = jc;
}

// ---------------- scatter tokens to per-expert rows + identity list ----------------
__global__ __launch_bounds__(256)
void scatter_jobs(const int* __restrict__ topi, const float* __restrict__ topw,
                  int* __restrict__ meta, int* __restrict__ glist,
                  float* __restrict__ job_w, int* __restrict__ t2r) {
    int t = blockIdx.x * 256 + threadIdx.x;
    if (t >= B_TOK) return;
    glist[4096 + t] = t;
    for (int k = 0; k < 2; ++k) {
        int e = topi[t * 2 + k];
        int pos = atomicAdd(&meta[16 + e], 1);
        int row = meta[32 + e] + pos;
        glist[row] = t;
        job_w[row] = topw[t * 2 + k];
        t2r[t * 2 + k] = row;
    }
}

// ---------------- G1 merged: dual GEMM + leaky*mul, bf16 out, 2-phase dbuf ----------
// BM=128 BN=64 BK=32; stage = A 4096 u16 + B1 2048 + B3 2048 = 8192 u16 (16KB), x2
__global__ __launch_bounds__(256)
void g1_dual(const u16* __restrict__ xb, const int* __restrict__ glist, const int* __restrict__ meta,
             const u16* __restrict__ w1b, const u16* __restrict__ w3b,
             const float* __restrict__ b1, const float* __restrict__ b3,
             const u16* __restrict__ sw1b, const u16* __restrict__ sw3b,
             const float* __restrict__ sb1, const float* __restrict__ sb3,
             u16* __restrict__ hbuf, u16* __restrict__ pbuf) {
    const int job = blockIdx.x;
    if (job >= meta[50]) return;
    const int e  = meta[64 + job];
    const int m0 = meta[128 + job];
    const bool sh = (e == 16);
    if (!sh && blockIdx.y >= (INTER / 64)) return;
    const int n0 = blockIdx.y * 64;
    const int N  = sh ? SH_INTER : INTER;
    const u16* B1 = sh ? sw1b : (w1b + (size_t)e * INTER * W_DIM);
    const u16* B3 = sh ? sw3b : (w3b + (size_t)e * INTER * W_DIM);
    const float* bb1 = sh ? sb1 : (b1 + (size_t)e * INTER);
    const float* bb3 = sh ? sb3 : (b3 + (size_t)e * INTER);
    const int abase = sh ? (4096 + m0) : (meta[32 + e] + m0);
    const int Mrows = (sh ? B_TOK : meta[e]) - m0;
    u16* outp = sh ? pbuf : hbuf;
    const int orow0 = sh ? m0 : (meta[32 + e] + m0);

    __shared__ __align__(16) u16 lds[2 * 8192];

    const int tid = threadIdx.x, lane = tid & 63, wv = tid >> 6;
    const int rA0 = tid >> 2, rA1 = rA0 + 64;
    const int kq = (tid & 3) * 8;
    const int tok0 = glist[abase + (rA0 < Mrows ? rA0 : Mrows - 1)];
    const int tok1 = glist[abase + (rA1 < Mrows ? rA1 : Mrows - 1)];
    const u16* gA0 = xb + (size_t)tok0 * W_DIM + kq;
    const u16* gA1 = xb + (size_t)tok1 * W_DIM + kq;
    const u16* gB1 = B1 + (size_t)(n0 + rA0) * W_DIM + kq;
    const u16* gB3 = B3 + (size_t)(n0 + rA0) * W_DIM + kq;

    const int wm = wv >> 1, wn = wv & 1;
    const int l15 = lane & 15, lhi = lane >> 4;

    f32x4 a1[4][2] = {};
    f32x4 a3[4][2] = {};

    auto stage = [&](int s, int k0) {
        u16* b = &lds[s * 8192];
        gld16(gA0 + k0, b + tid * 8);
        gld16(gA1 + k0, b + 2048 + tid * 8);
        gld16(gB1 + k0, b + 4096 + tid * 8);
        gld16(gB3 + k0, b + 6144 + tid * 8);
    };

    int cur = 0;
    stage(0, 0);
    for (int t = 0; t < W_DIM / 32; ++t) {
        __syncthreads();                       // vmcnt(0): buf[cur] ready; prev reads done
        if (t < W_DIM / 32 - 1) stage(cur ^ 1, (t + 1) * 32);
        const u16* bb = &lds[cur * 8192];
        bf16x8 af[4], f1[2], f3[2];
        #pragma unroll
        for (int i = 0; i < 4; ++i)
            af[i] = *(const bf16x8*)&bb[(wm * 64 + i * 16 + l15) * 32 + lhi * 8];
        #pragma unroll
        for (int j = 0; j < 2; ++j) {
            f1[j] = *(const bf16x8*)&bb[4096 + (wn * 32 + j * 16 + l15) * 32 + lhi * 8];
            f3[j] = *(const bf16x8*)&bb[6144 + (wn * 32 + j * 16 + l15) * 32 + lhi * 8];
        }
        #pragma unroll
        for (int i = 0; i < 4; ++i)
            #pragma unroll
            for (int j = 0; j < 2; ++j) {
                a1[i][j] = __builtin_amdgcn_mfma_f32_16x16x32_bf16(af[i], f1[j], a1[i][j], 0, 0, 0);
                a3[i][j] = __builtin_amdgcn_mfma_f32_16x16x32_bf16(af[i], f3[j], a3[i][j], 0, 0, 0);
            }
        cur ^= 1;
    }

    #pragma unroll
    for (int i = 0; i < 4; ++i)
    #pragma unroll
    for (int j = 0; j < 2; ++j) {
        const int col = n0 + wn * 32 + j * 16 + l15;
        const float vb1 = bb1[col];
        const float vb3 = bb3[col];
        #pragma unroll
        for (int r = 0; r < 4; ++r) {
            const int gm = wm * 64 + i * 16 + lhi * 4 + r;
            if (gm < Mrows) {
                float v1 = a1[i][j][r] + vb1;
                float v3 = a3[i][j][r] + vb3;
                v1 = v1 >= 0.f ? v1 : 0.01f * v1;
                outp[(size_t)(orow0 + gm) * N + col] = f2b(v1 * v3);
            }
        }
    }
}

// ---------------- G2 merged: GEMM + bias (+scale), fp32 out, 2-phase dbuf ----------
// BM=64 BN=64 BK=32; stage = 2048 + 2048 u16 (8KB), x2
__global__ __launch_bounds__(256)
void g2_gemm(const int* __restrict__ meta,
             const u16* __restrict__ hbuf, const u16* __restrict__ pbuf,
             const u16* __restrict__ w2b, const float* __restrict__ b2,
             const u16* __restrict__ sw2b, const float* __restrict__ sb2,
             const float* __restrict__ job_w,
             float* __restrict__ y2, float* __restrict__ zbuf) {
    const int job = blockIdx.x;
    if (job >= meta[51]) return;
    const int e  = meta[192 + job];
    const int m0 = meta[304 + job];
    const bool sh = (e == 16);
    const int n0 = blockIdx.y * 64;
    const int K  = sh ? SH_INTER : INTER;
    const u16* A = sh ? pbuf : hbuf;
    const int Arow0 = sh ? m0 : (meta[32 + e] + m0);
    const u16* Bw = sh ? sw2b : (w2b + (size_t)e * W_DIM * INTER);
    const float* bias = sh ? sb2 : (b2 + (size_t)e * W_DIM);
    const int Mrows = (sh ? B_TOK : meta[e]) - m0;
    const float* scale = sh ? nullptr : (job_w + Arow0);
    float* outp = sh ? zbuf : y2;

    __shared__ __align__(16) u16 lds[2 * 4096];

    const int tid = threadIdx.x, lane = tid & 63, wv = tid >> 6;
    const int rA = tid >> 2;
    const int kq = (tid & 3) * 8;
    const u16* gA = A + (size_t)(Arow0 + (rA < Mrows ? rA : Mrows - 1)) * K + kq;
    const u16* gB = Bw + (size_t)(n0 + rA) * K + kq;

    const int wm = wv >> 1, wn = wv & 1;
    const int l15 = lane & 15, lhi = lane >> 4;

    f32x4 acc[2][2] = {};

    auto stage = [&](int s, int k0) {
        u16* b = &lds[s * 4096];
        gld16(gA + k0, b + tid * 8);
        gld16(gB + k0, b + 2048 + tid * 8);
    };

    const int NT = K / 32;
    int cur = 0;
    stage(0, 0);
    for (int t = 0; t < NT; ++t) {
        __syncthreads();
        if (t < NT - 1) stage(cur ^ 1, (t + 1) * 32);
        const u16* bb = &lds[cur * 4096];
        bf16x8 af[2], bf[2];
        #pragma unroll
        for (int i = 0; i < 2; ++i)
            af[i] = *(const bf16x8*)&bb[(wm * 32 + i * 16 + l15) * 32 + lhi * 8];
        #pragma unroll
        for (int j = 0; j < 2; ++j)
            bf[j] = *(const bf16x8*)&bb[2048 + (wn * 32 + j * 16 + l15) * 32 + lhi * 8];
        #pragma unroll
        for (int i = 0; i < 2; ++i)
            #pragma unroll
            for (int j = 0; j < 2; ++j)
                acc[i][j] = __builtin_amdgcn_mfma_f32_16x16x32_bf16(af[i], bf[j], acc[i][j], 0, 0, 0);
        cur ^= 1;
    }

    #pragma unroll
    for (int i = 0; i < 2; ++i)
    #pragma unroll
    for (int j = 0; j < 2; ++j) {
        const int col = n0 + wn * 32 + j * 16 + l15;
        const float bb = bias[col];
        #pragma unroll
        for (int r = 0; r < 4; ++r) {
            const int gm = wm * 32 + i * 16 + lhi * 4 + r;
            if (gm < Mrows) {
                float v = acc[i][j][r] + bb;
                if (scale) v *= scale[gm];
                outp[(size_t)(Arow0 + gm) * W_DIM + col] = v;
            }
        }
    }
}

// ---------------- combine: ybf = bf16(y2[r0] + y2[r1] + z) ----------------
__global__ __launch_bounds__(256)
void combine_k(const float* __restrict__ y2, const float* __restrict__ z,
               const int* __restrict__ t2r, u16* __restrict__ ybf) {
    int idx = blockIdx.x * 256 + threadIdx.x;
    int t = idx >> 7;
    int w4 = (idx & 127) << 2;
    int r0 = t2r[t * 2 + 0], r1 = t2r[t * 2 + 1];
    const float4 a = *(const float4*)(y2 + (size_t)r0 * W_DIM + w4);
    const float4 b = *(const float4*)(y2 + (size_t)r1 * W_DIM + w4);
    const float4 c = *(const float4*)(z + (size_t)t * W_DIM + w4);
    ushort4 o;
    o.x = f2b(a.x + b.x + c.x);
    o.y = f2b(a.y + b.y + c.y);
    o.z = f2b(a.z + b.z + c.z);
    o.w = f2b(a.w + b.w + c.w);
    *(ushort4*)(ybf + (size_t)t * W_DIM + w4) = o;
}

// ---------------- output projection: out = ybf @ ow^T + ob ----------------
__global__ __launch_bounds__(256)
void gout(const u16* __restrict__ ybf, const u16* __restrict__ owb,
          const float* __restrict__ ob, float* __restrict__ out) {
    const int m0 = blockIdx.x * 64, n0 = blockIdx.y * 64;
    __shared__ __align__(16) u16 lds[2 * 4096];
    const int tid = threadIdx.x, lane = tid & 63, wv = tid >> 6;
    const int rA = tid >> 2;
    const int kq = (tid & 3) * 8;
    const u16* gA = ybf + (size_t)(m0 + rA) * W_DIM + kq;
    const u16* gB = owb + (size_t)(n0 + rA) * W_DIM + kq;
    const int wm = wv >> 1, wn = wv & 1;
    const int l15 = lane & 15, lhi = lane >> 4;
    f32x4 acc[2][2] = {};
    auto stage = [&](int s, int k0) {
        u16* b = &lds[s * 4096];
        gld16(gA + k0, b + tid * 8);
        gld16(gB + k0, b + 2048 + tid * 8);
    };
    int cur = 0;
    stage(0, 0);
    for (int t = 0; t < W_DIM / 32; ++t) {
        __syncthreads();
        if (t < W_DIM / 32 - 1) stage(cur ^ 1, (t + 1) * 32);
        const u16* bb = &lds[cur * 4096];
        bf16x8 af[2], bf[2];
        #pragma unroll
        for (int i = 0; i < 2; ++i)
            af[i] = *(const bf16x8*)&bb[(wm * 32 + i * 16 + l15) * 32 + lhi * 8];
        #pragma unroll
        for (int j = 0; j < 2; ++j)
            bf[j] = *(const bf16x8*)&bb[2048 + (wn * 32 + j * 16 + l15) * 32 + lhi * 8];
        #pragma unroll
        for (int i = 0; i < 2; ++i)
            #pragma unroll
            for (int j = 0; j < 2; ++j)
                acc[i][j] = __builtin_amdgcn_mfma_f32_16x16x32_bf16(af[i], bf[j], acc[i][j], 0, 0, 0);
        cur ^= 1;
    }
    #pragma unroll
    for (int i = 0; i < 2; ++i)
    #pragma unroll
    for (int j = 0; j < 2; ++j) {
        const int col = n0 + wn * 32 + j * 16 + l15;
        if (col < OUT_DIM) {
            const float bb = ob[col];
            #pragma unroll
            for (int r = 0; r < 4; ++r) {
                const int gm = wm * 32 + i * 16 + lhi * 4 + r;
                out[(size_t)(m0 + gm) * OUT_DIM + col] = acc[i][j][r] + bb;
            }
        }
    }
}

extern "C" void kernel_launch(void* const* d_in, const int* in_sizes, int n_in,
                              void* d_out, int out_size, void* d_ws, size_t ws_size,
                              hipStream_t stream) {
    const float* x      = (const float*)d_in[0];
    const float* gate_w = (const float*)d_in[2];
    const float* w1     = (const float*)d_in[3];
    const float* b1     = (const float*)d_in[4];
    const float* w2     = (const float*)d_in[5];
    const float* b2     = (const float*)d_in[6];
    const float* w3     = (const float*)d_in[7];
    const float* b3     = (const float*)d_in[8];
    const float* sw1    = (const float*)d_in[9];
    const float* sb1    = (const float*)d_in[10];
    const float* sw2    = (const float*)d_in[11];
    const float* sb2    = (const float*)d_in[12];
    const float* sw3    = (const float*)d_in[13];
    const float* sb3    = (const float*)d_in[14];
    const float* ow     = (const float*)d_in[15];
    const float* ob     = (const float*)d_in[16];
    float* out = (float*)d_out;

    char* ws = (char*)d_ws;
    size_t off = 0;
    auto alloc = [&](size_t bytes) -> void* {
        void* p = (void*)(ws + off);
        off += (bytes + 255) & ~(size_t)255;
        return p;
    };

    int*   meta   = (int*)alloc(2048);
    int*   topi   = (int*)alloc((size_t)B_TOK * 2 * 4);
    float* topw   = (float*)alloc((size_t)B_TOK * 2 * 4);
    int*   t2r    = (int*)alloc((size_t)B_TOK * 2 * 4);
    int*   glist  = (int*)alloc((size_t)(B_TOK * 2 + B_TOK) * 4);
    float* job_w  = (float*)alloc((size_t)B_TOK * 2 * 4);
    u16*   xb     = (u16*)alloc((size_t)B_TOK * W_DIM * 2);
    u16*   w1b    = (u16*)alloc((size_t)E_N * INTER * W_DIM * 2);
    u16*   w3b    = (u16*)alloc((size_t)E_N * INTER * W_DIM * 2);
    u16*   w2b    = (u16*)alloc((size_t)E_N * W_DIM * INTER * 2);
    u16*   sw1b   = (u16*)alloc((size_t)SH_INTER * W_DIM * 2);
    u16*   sw3b   = (u16*)alloc((size_t)SH_INTER * W_DIM * 2);
    u16*   sw2b   = (u16*)alloc((size_t)W_DIM * SH_INTER * 2);
    u16*   owb    = (u16*)alloc((size_t)OUT_DIM * W_DIM * 2);
    u16*   hbuf   = (u16*)alloc((size_t)B_TOK * 2 * INTER * 2);
    u16*   pbuf   = (u16*)alloc((size_t)B_TOK * SH_INTER * 2);
    float* y2     = (float*)alloc((size_t)B_TOK * 2 * W_DIM * 4);
    float* zbuf   = (float*)alloc((size_t)B_TOK * W_DIM * 4);
    u16*   ybf    = (u16*)alloc((size_t)B_TOK * W_DIM * 2);
    if (off > ws_size) return;

    dim3 blk(256);

    CastArgs ca;
    ca.s[0] = { (const float4*)x,   (ushort4*)xb,   B_TOK * W_DIM / 4 };
    ca.s[1] = { (const float4*)w1,  (ushort4*)w1b,  E_N * INTER * W_DIM / 4 };
    ca.s[2] = { (const float4*)w3,  (ushort4*)w3b,  E_N * INTER * W_DIM / 4 };
    ca.s[3] = { (const float4*)w2,  (ushort4*)w2b,  E_N * W_DIM * INTER / 4 };
    ca.s[4] = { (const float4*)sw1, (ushort4*)sw1b, SH_INTER * W_DIM / 4 };
    ca.s[5] = { (const float4*)sw3, (ushort4*)sw3b, SH_INTER * W_DIM / 4 };
    ca.s[6] = { (const float4*)sw2, (ushort4*)sw2b, W_DIM * SH_INTER / 4 };
    ca.s[7] = { (const float4*)ow,  (ushort4*)owb,  OUT_DIM * W_DIM / 4 };
    ca.total4 = 0;
    for (int i = 0; i < 8; ++i) ca.total4 += ca.s[i].n4;
    ca.meta = meta;
    cast_all<<<dim3(2048), blk, 0, stream>>>(ca);

    gate_topk<<<dim3(B_TOK / 4), blk, 0, stream>>>(x, gate_w, topi, topw, meta);
    build_jobs<<<1, 64, 0, stream>>>(meta);
    scatter_jobs<<<dim3(B_TOK / 256), blk, 0, stream>>>(topi, topw, meta, glist, job_w, t2r);

    // g1 merged: routed (<=48 jobs) + shared (16 jobs); grid.x = 64 upper bound
    g1_dual<<<dim3(64, SH_INTER / 64), blk, 0, stream>>>(
        xb, glist, meta, w1b, w3b, b1, b3, sw1b, sw3b, sb1, sb3, hbuf, pbuf);

    // g2 merged: routed (<=80 jobs) + shared (32 jobs); grid.x = 112 upper bound
    g2_gemm<<<dim3(112, W_DIM / 64), blk, 0, stream>>>(
        meta, hbuf, pbuf, w2b, b2, sw2b, sb2, job_w, y2, zbuf);

    combine_k<<<dim3(B_TOK * W_DIM / 4 / 256), blk, 0, stream>>>(y2, zbuf, t2r, ybf);

    gout<<<dim3(B_TOK / 64, 2), blk, 0, stream>>>(ybf, owb, ob, out);
}

// Round 3
// 148.880 us; speedup vs baseline: 2.5768x; 1.2942x over previous
//
#include <hip/hip_runtime.h>

#define B_TOK 2048
#define W_DIM 512
#define E_N 16
#define INTER 1024
#define SH_INTER 2048
#define OUT_DIM 128

typedef unsigned short u16;
typedef unsigned int u32;
typedef __attribute__((ext_vector_type(8))) short bf16x8;
typedef __attribute__((ext_vector_type(4))) float f32x4;

__device__ __forceinline__ u16 f2b(float f) {
    union { float f; unsigned u; } x; x.f = f;
    unsigned r = x.u + 0x7FFFu + ((x.u >> 16) & 1u);
    return (u16)(r >> 16);
}

__device__ __forceinline__ u32 cvtpk(float lo, float hi) {
    u32 r;
    asm("v_cvt_pk_bf16_f32 %0, %1, %2" : "=v"(r) : "v"(lo), "v"(hi));
    return r;
}

// pack 8 fp32 (two float4) -> 8 bf16 (uint4), elem order preserved
__device__ __forceinline__ uint4 pk8(const float4* v) {
    uint4 o;
    o.x = cvtpk(v[0].x, v[0].y);
    o.y = cvtpk(v[0].z, v[0].w);
    o.z = cvtpk(v[1].x, v[1].y);
    o.w = cvtpk(v[1].z, v[1].w);
    return o;
}

__device__ __forceinline__ void gld16(const void* g, void* l) {
    __builtin_amdgcn_global_load_lds(
        (const __attribute__((address_space(1))) void*)g,
        (__attribute__((address_space(3))) void*)l, 16, 0, 0);
}

// meta layout (ints):
// [0..15] counts  [32..47] offs
// [50] n_j1  [51] n_j2
// [64..127] j1e  [128..191] j1m   (g1 jobs, BM=128)
// [192..303] j2e [304..415] j2m   (g2 jobs, BM=64)

// ---------------- gate: fp32 logits, softmax, top-2 (NO atomics) ----------------
__global__ __launch_bounds__(256)
void gate_topk(const float* __restrict__ x, const float* __restrict__ gw,
               int* __restrict__ topi, float* __restrict__ topw) {
    const int lane = threadIdx.x & 63;
    const int wv   = threadIdx.x >> 6;
    const int t    = blockIdx.x * 4 + wv;
    const int e = lane >> 2, q = lane & 3;
    const float4* xr = (const float4*)(x + (size_t)t * W_DIM);
    const float4* wr = (const float4*)(gw + (size_t)e * W_DIM);
    float s = 0.f;
    #pragma unroll
    for (int i = 0; i < W_DIM / 16; ++i) {
        float4 a = xr[q + 4 * i];
        float4 b = wr[q + 4 * i];
        s += a.x * b.x + a.y * b.y + a.z * b.z + a.w * b.w;
    }
    s += __shfl_xor(s, 1);
    s += __shfl_xor(s, 2);
    float sc[16];
    #pragma unroll
    for (int ee = 0; ee < 16; ++ee) sc[ee] = __shfl(s, ee * 4);
    float mx = sc[0];
    #pragma unroll
    for (int ee = 1; ee < 16; ++ee) mx = fmaxf(mx, sc[ee]);
    float p[16]; float sum = 0.f;
    #pragma unroll
    for (int ee = 0; ee < 16; ++ee) { p[ee] = expf(sc[ee] - mx); sum += p[ee]; }
    const float inv = 1.f / sum;
    int i0 = 0; float v0 = sc[0];
    #pragma unroll
    for (int ee = 1; ee < 16; ++ee) if (sc[ee] > v0) { v0 = sc[ee]; i0 = ee; }
    int i1 = -1; float v1 = -1e30f;
    #pragma unroll
    for (int ee = 0; ee < 16; ++ee) if (ee != i0 && sc[ee] > v1) { v1 = sc[ee]; i1 = ee; }
    if (lane == 0) {
        topi[t * 2 + 0] = i0; topi[t * 2 + 1] = i1;
        topw[t * 2 + 0] = p[i0] * inv; topw[t * 2 + 1] = p[i1] * inv;
    }
}

// ---------------- route_build: single block, LDS atomics only ----------------
__global__ __launch_bounds__(256)
void route_build(const int* __restrict__ topi, const float* __restrict__ topw,
                 int* __restrict__ meta, int* __restrict__ glist,
                 float* __restrict__ job_w, int* __restrict__ t2r) {
    __shared__ int cnt[16], cur[16], offs[16];
    const int tid = threadIdx.x;
    if (tid < 16) { cnt[tid] = 0; cur[tid] = 0; }
    __syncthreads();
    for (int i = tid; i < 2 * B_TOK; i += 256) atomicAdd(&cnt[topi[i]], 1);
    __syncthreads();
    if (tid == 0) {
        int acc = 0, jc = 0;
        for (int e = 0; e < 16; ++e) {
            offs[e] = acc; meta[e] = cnt[e]; meta[32 + e] = acc; acc += cnt[e];
        }
        for (int e = 0; e < 16; ++e)
            for (int m = 0; m < cnt[e]; m += 128) { meta[64 + jc] = e; meta[128 + jc] = m; ++jc; }
        for (int m = 0; m < B_TOK; m += 128) { meta[64 + jc] = 16; meta[128 + jc] = m; ++jc; }
        meta[50] = jc;
        jc = 0;
        for (int e = 0; e < 16; ++e)
            for (int m = 0; m < cnt[e]; m += 64) { meta[192 + jc] = e; meta[304 + jc] = m; ++jc; }
        for (int m = 0; m < B_TOK; m += 64) { meta[192 + jc] = 16; meta[304 + jc] = m; ++jc; }
        meta[51] = jc;
    }
    __syncthreads();
    for (int i = tid; i < 2 * B_TOK; i += 256) {
        int e = topi[i];
        int pos = atomicAdd(&cur[e], 1);
        int row = offs[e] + pos;
        glist[row] = i >> 1;
        job_w[row] = topw[i];
        t2r[i] = row;
    }
    for (int t = tid; t < B_TOK; t += 256) glist[4096 + t] = t;
}

// ---------------- G1 merged: dual GEMM + leaky*mul, fp32 in (reg-staged), bf16 out --
// BM=128 BN=64 BK=32; LDS: A 4096 u16 + B1 2048 + B3 2048 = 8192 u16 (16KB), x2
__global__ __launch_bounds__(256)
void g1_dual(const float* __restrict__ x, const int* __restrict__ glist, const int* __restrict__ meta,
             const float* __restrict__ w1, const float* __restrict__ w3,
             const float* __restrict__ b1, const float* __restrict__ b3,
             const float* __restrict__ sw1, const float* __restrict__ sw3,
             const float* __restrict__ sb1, const float* __restrict__ sb3,
             u16* __restrict__ hbuf, u16* __restrict__ pbuf) {
    const int job = blockIdx.x;
    if (job >= meta[50]) return;
    const int e  = meta[64 + job];
    const int m0 = meta[128 + job];
    const bool sh = (e == 16);
    if (!sh && blockIdx.y >= (INTER / 64)) return;
    const int n0 = blockIdx.y * 64;
    const int N  = sh ? SH_INTER : INTER;
    const float* B1 = sh ? sw1 : (w1 + (size_t)e * INTER * W_DIM);
    const float* B3 = sh ? sw3 : (w3 + (size_t)e * INTER * W_DIM);
    const float* bb1 = sh ? sb1 : (b1 + (size_t)e * INTER);
    const float* bb3 = sh ? sb3 : (b3 + (size_t)e * INTER);
    const int abase = sh ? (4096 + m0) : (meta[32 + e] + m0);
    const int Mrows = (sh ? B_TOK : meta[e]) - m0;
    u16* outp = sh ? pbuf : hbuf;
    const int orow0 = sh ? m0 : (meta[32 + e] + m0);

    __shared__ __align__(16) u16 lds[2 * 8192];

    const int tid = threadIdx.x, lane = tid & 63, wv = tid >> 6;
    const int rA0 = tid >> 2, rA1 = rA0 + 64;
    const int kq = (tid & 3) * 8;
    const int tok0 = glist[abase + (rA0 < Mrows ? rA0 : Mrows - 1)];
    const int tok1 = glist[abase + (rA1 < Mrows ? rA1 : Mrows - 1)];
    const float* gA0 = x + (size_t)tok0 * W_DIM + kq;
    const float* gA1 = x + (size_t)tok1 * W_DIM + kq;
    const float* gB1 = B1 + (size_t)(n0 + rA0) * W_DIM + kq;
    const float* gB3 = B3 + (size_t)(n0 + rA0) * W_DIM + kq;

    const int wm = wv >> 1, wn = wv & 1;
    const int l15 = lane & 15, lhi = lane >> 4;

    f32x4 a1[4][2] = {};
    f32x4 a3[4][2] = {};

    float4 ra0[2], ra1[2], rb1[2], rb3[2];
    auto gload = [&](int k0) {
        ra0[0] = *(const float4*)(gA0 + k0); ra0[1] = *(const float4*)(gA0 + k0 + 4);
        ra1[0] = *(const float4*)(gA1 + k0); ra1[1] = *(const float4*)(gA1 + k0 + 4);
        rb1[0] = *(const float4*)(gB1 + k0); rb1[1] = *(const float4*)(gB1 + k0 + 4);
        rb3[0] = *(const float4*)(gB3 + k0); rb3[1] = *(const float4*)(gB3 + k0 + 4);
    };
    auto swrite = [&](int s) {
        u16* b = &lds[s * 8192];
        *(uint4*)(b + tid * 8)        = pk8(ra0);
        *(uint4*)(b + 2048 + tid * 8) = pk8(ra1);
        *(uint4*)(b + 4096 + tid * 8) = pk8(rb1);
        *(uint4*)(b + 6144 + tid * 8) = pk8(rb3);
    };

    const int NT = W_DIM / 32;
    int cur = 0;
    gload(0);
    swrite(0);
    for (int t = 0; t < NT; ++t) {
        __syncthreads();
        if (t + 1 < NT) gload((t + 1) * 32);     // issue early (T14)
        const u16* bb = &lds[cur * 8192];
        bf16x8 af[4], f1[2], f3[2];
        #pragma unroll
        for (int i = 0; i < 4; ++i)
            af[i] = *(const bf16x8*)&bb[(wm * 64 + i * 16 + l15) * 32 + lhi * 8];
        #pragma unroll
        for (int j = 0; j < 2; ++j) {
            f1[j] = *(const bf16x8*)&bb[4096 + (wn * 32 + j * 16 + l15) * 32 + lhi * 8];
            f3[j] = *(const bf16x8*)&bb[6144 + (wn * 32 + j * 16 + l15) * 32 + lhi * 8];
        }
        #pragma unroll
        for (int i = 0; i < 4; ++i)
            #pragma unroll
            for (int j = 0; j < 2; ++j) {
                a1[i][j] = __builtin_amdgcn_mfma_f32_16x16x32_bf16(af[i], f1[j], a1[i][j], 0, 0, 0);
                a3[i][j] = __builtin_amdgcn_mfma_f32_16x16x32_bf16(af[i], f3[j], a3[i][j], 0, 0, 0);
            }
        if (t + 1 < NT) swrite(cur ^ 1);         // write late, after this tile's ds_reads
        cur ^= 1;
    }

    #pragma unroll
    for (int i = 0; i < 4; ++i)
    #pragma unroll
    for (int j = 0; j < 2; ++j) {
        const int col = n0 + wn * 32 + j * 16 + l15;
        const float vb1 = bb1[col];
        const float vb3 = bb3[col];
        #pragma unroll
        for (int r = 0; r < 4; ++r) {
            const int gm = wm * 64 + i * 16 + lhi * 4 + r;
            if (gm < Mrows) {
                float v1 = a1[i][j][r] + vb1;
                float v3 = a3[i][j][r] + vb3;
                v1 = v1 >= 0.f ? v1 : 0.01f * v1;
                outp[(size_t)(orow0 + gm) * N + col] = f2b(v1 * v3);
            }
        }
    }
}

// ---------------- G2 merged: A bf16 (gld16) x B fp32 (reg-staged), fp32 out ------
// BM=64 BN=64 BK=32
__global__ __launch_bounds__(256)
void g2_gemm(const int* __restrict__ meta,
             const u16* __restrict__ hbuf, const u16* __restrict__ pbuf,
             const float* __restrict__ w2, const float* __restrict__ b2,
             const float* __restrict__ sw2, const float* __restrict__ sb2,
             const float* __restrict__ job_w,
             float* __restrict__ y2, float* __restrict__ zbuf) {
    const int job = blockIdx.x;
    if (job >= meta[51]) return;
    const int e  = meta[192 + job];
    const int m0 = meta[304 + job];
    const bool sh = (e == 16);
    const int n0 = blockIdx.y * 64;
    const int K  = sh ? SH_INTER : INTER;
    const u16* A = sh ? pbuf : hbuf;
    const int Arow0 = sh ? m0 : (meta[32 + e] + m0);
    const float* Bw = sh ? sw2 : (w2 + (size_t)e * W_DIM * INTER);
    const float* bias = sh ? sb2 : (b2 + (size_t)e * W_DIM);
    const int Mrows = (sh ? B_TOK : meta[e]) - m0;
    const float* scale = sh ? nullptr : (job_w + Arow0);
    float* outp = sh ? zbuf : y2;

    __shared__ __align__(16) u16 lds[2 * 4096];

    const int tid = threadIdx.x, lane = tid & 63, wv = tid >> 6;
    const int rA = tid >> 2;
    const int kq = (tid & 3) * 8;
    const u16*   gA = A + (size_t)(Arow0 + (rA < Mrows ? rA : Mrows - 1)) * K + kq;
    const float* gB = Bw + (size_t)(n0 + rA) * K + kq;

    const int wm = wv >> 1, wn = wv & 1;
    const int l15 = lane & 15, lhi = lane >> 4;

    f32x4 acc[2][2] = {};

    float4 rb[2];
    auto stageA = [&](int s, int k0) { gld16(gA + k0, &lds[s * 4096] + tid * 8); };
    auto gloadB = [&](int k0) {
        rb[0] = *(const float4*)(gB + k0); rb[1] = *(const float4*)(gB + k0 + 4);
    };
    auto swriteB = [&](int s) { *(uint4*)(&lds[s * 4096] + 2048 + tid * 8) = pk8(rb); };

    const int NT = K / 32;
    int cur = 0;
    stageA(0, 0);
    gloadB(0);
    swriteB(0);
    for (int t = 0; t < NT; ++t) {
        __syncthreads();
        if (t + 1 < NT) { stageA(cur ^ 1, (t + 1) * 32); gloadB((t + 1) * 32); }
        const u16* bb = &lds[cur * 4096];
        bf16x8 af[2], bf[2];
        #pragma unroll
        for (int i = 0; i < 2; ++i)
            af[i] = *(const bf16x8*)&bb[(wm * 32 + i * 16 + l15) * 32 + lhi * 8];
        #pragma unroll
        for (int j = 0; j < 2; ++j)
            bf[j] = *(const bf16x8*)&bb[2048 + (wn * 32 + j * 16 + l15) * 32 + lhi * 8];
        #pragma unroll
        for (int i = 0; i < 2; ++i)
            #pragma unroll
            for (int j = 0; j < 2; ++j)
                acc[i][j] = __builtin_amdgcn_mfma_f32_16x16x32_bf16(af[i], bf[j], acc[i][j], 0, 0, 0);
        if (t + 1 < NT) swriteB(cur ^ 1);
        cur ^= 1;
    }

    #pragma unroll
    for (int i = 0; i < 2; ++i)
    #pragma unroll
    for (int j = 0; j < 2; ++j) {
        const int col = n0 + wn * 32 + j * 16 + l15;
        const float bb = bias[col];
        #pragma unroll
        for (int r = 0; r < 4; ++r) {
            const int gm = wm * 32 + i * 16 + lhi * 4 + r;
            if (gm < Mrows) {
                float v = acc[i][j][r] + bb;
                if (scale) v *= scale[gm];
                outp[(size_t)(Arow0 + gm) * W_DIM + col] = v;
            }
        }
    }
}

// ---------------- combine: ybf = bf16(y2[r0] + y2[r1] + z) ----------------
__global__ __launch_bounds__(256)
void combine_k(const float* __restrict__ y2, const float* __restrict__ z,
               const int* __restrict__ t2r, u16* __restrict__ ybf) {
    int idx = blockIdx.x * 256 + threadIdx.x;
    int t = idx >> 7;
    int w4 = (idx & 127) << 2;
    int r0 = t2r[t * 2 + 0], r1 = t2r[t * 2 + 1];
    const float4 a = *(const float4*)(y2 + (size_t)r0 * W_DIM + w4);
    const float4 b = *(const float4*)(y2 + (size_t)r1 * W_DIM + w4);
    const float4 c = *(const float4*)(z + (size_t)t * W_DIM + w4);
    ushort4 o;
    o.x = f2b(a.x + b.x + c.x);
    o.y = f2b(a.y + b.y + c.y);
    o.z = f2b(a.z + b.z + c.z);
    o.w = f2b(a.w + b.w + c.w);
    *(ushort4*)(ybf + (size_t)t * W_DIM + w4) = o;
}

// ---------------- output projection: out = ybf @ ow^T + ob (ow fp32) ----------
__global__ __launch_bounds__(256)
void gout(const u16* __restrict__ ybf, const float* __restrict__ ow,
          const float* __restrict__ ob, float* __restrict__ out) {
    const int m0 = blockIdx.x * 64, n0 = blockIdx.y * 64;
    __shared__ __align__(16) u16 lds[2 * 4096];
    const int tid = threadIdx.x, lane = tid & 63, wv = tid >> 6;
    const int rA = tid >> 2;
    const int kq = (tid & 3) * 8;
    const u16*   gA = ybf + (size_t)(m0 + rA) * W_DIM + kq;
    const float* gB = ow + (size_t)(n0 + rA) * W_DIM + kq;
    const int wm = wv >> 1, wn = wv & 1;
    const int l15 = lane & 15, lhi = lane >> 4;
    f32x4 acc[2][2] = {};
    float4 rb[2];
    auto stageA = [&](int s, int k0) { gld16(gA + k0, &lds[s * 4096] + tid * 8); };
    auto gloadB = [&](int k0) {
        rb[0] = *(const float4*)(gB + k0); rb[1] = *(const float4*)(gB + k0 + 4);
    };
    auto swriteB = [&](int s) { *(uint4*)(&lds[s * 4096] + 2048 + tid * 8) = pk8(rb); };
    const int NT = W_DIM / 32;
    int cur = 0;
    stageA(0, 0);
    gloadB(0);
    swriteB(0);
    for (int t = 0; t < NT; ++t) {
        __syncthreads();
        if (t + 1 < NT) { stageA(cur ^ 1, (t + 1) * 32); gloadB((t + 1) * 32); }
        const u16* bb = &lds[cur * 4096];
        bf16x8 af[2], bf[2];
        #pragma unroll
        for (int i = 0; i < 2; ++i)
            af[i] = *(const bf16x8*)&bb[(wm * 32 + i * 16 + l15) * 32 + lhi * 8];
        #pragma unroll
        for (int j = 0; j < 2; ++j)
            bf[j] = *(const bf16x8*)&bb[2048 + (wn * 32 + j * 16 + l15) * 32 + lhi * 8];
        #pragma unroll
        for (int i = 0; i < 2; ++i)
            #pragma unroll
            for (int j = 0; j < 2; ++j)
                acc[i][j] = __builtin_amdgcn_mfma_f32_16x16x32_bf16(af[i], bf[j], acc[i][j], 0, 0, 0);
        if (t + 1 < NT) swriteB(cur ^ 1);
        cur ^= 1;
    }
    #pragma unroll
    for (int i = 0; i < 2; ++i)
    #pragma unroll
    for (int j = 0; j < 2; ++j) {
        const int col = n0 + wn * 32 + j * 16 + l15;
        if (col < OUT_DIM) {
            const float bb = ob[col];
            #pragma unroll
            for (int r = 0; r < 4; ++r) {
                const int gm = wm * 32 + i * 16 + lhi * 4 + r;
                out[(size_t)(m0 + gm) * OUT_DIM + col] = acc[i][j][r] + bb;
            }
        }
    }
}

extern "C" void kernel_launch(void* const* d_in, const int* in_sizes, int n_in,
                              void* d_out, int out_size, void* d_ws, size_t ws_size,
                              hipStream_t stream) {
    const float* x      = (const float*)d_in[0];
    const float* gate_w = (const float*)d_in[2];
    const float* w1     = (const float*)d_in[3];
    const float* b1     = (const float*)d_in[4];
    const float* w2     = (const float*)d_in[5];
    const float* b2     = (const float*)d_in[6];
    const float* w3     = (const float*)d_in[7];
    const float* b3     = (const float*)d_in[8];
    const float* sw1    = (const float*)d_in[9];
    const float* sb1    = (const float*)d_in[10];
    const float* sw2    = (const float*)d_in[11];
    const float* sb2    = (const float*)d_in[12];
    const float* sw3    = (const float*)d_in[13];
    const float* sb3    = (const float*)d_in[14];
    const float* ow     = (const float*)d_in[15];
    const float* ob     = (const float*)d_in[16];
    float* out = (float*)d_out;

    char* ws = (char*)d_ws;
    size_t off = 0;
    auto alloc = [&](size_t bytes) -> void* {
        void* p = (void*)(ws + off);
        off += (bytes + 255) & ~(size_t)255;
        return p;
    };

    int*   meta   = (int*)alloc(2048);
    int*   topi   = (int*)alloc((size_t)B_TOK * 2 * 4);
    float* topw   = (float*)alloc((size_t)B_TOK * 2 * 4);
    int*   t2r    = (int*)alloc((size_t)B_TOK * 2 * 4);
    int*   glist  = (int*)alloc((size_t)(B_TOK * 2 + B_TOK) * 4);
    float* job_w  = (float*)alloc((size_t)B_TOK * 2 * 4);
    u16*   hbuf   = (u16*)alloc((size_t)B_TOK * 2 * INTER * 2);
    u16*   pbuf   = (u16*)alloc((size_t)B_TOK * SH_INTER * 2);
    float* y2     = (float*)alloc((size_t)B_TOK * 2 * W_DIM * 4);
    float* zbuf   = (float*)alloc((size_t)B_TOK * W_DIM * 4);
    u16*   ybf    = (u16*)alloc((size_t)B_TOK * W_DIM * 2);
    if (off > ws_size) return;

    dim3 blk(256);

    gate_topk<<<dim3(B_TOK / 4), blk, 0, stream>>>(x, gate_w, topi, topw);
    route_build<<<1, blk, 0, stream>>>(topi, topw, meta, glist, job_w, t2r);

    // g1 merged: routed (<=48 jobs) + shared (16 jobs)
    g1_dual<<<dim3(64, SH_INTER / 64), blk, 0, stream>>>(
        x, glist, meta, w1, w3, b1, b3, sw1, sw3, sb1, sb3, hbuf, pbuf);

    // g2 merged: routed (<=80 jobs) + shared (32 jobs)
    g2_gemm<<<dim3(112, W_DIM / 64), blk, 0, stream>>>(
        meta, hbuf, pbuf, w2, b2, sw2, sb2, job_w, y2, zbuf);

    combine_k<<<dim3(B_TOK * W_DIM / 4 / 256), blk, 0, stream>>>(y2, zbuf, t2r, ybf);

    gout<<<dim3(B_TOK / 64, 2), blk, 0, stream>>>(ybf, ow, ob, out);
}

// Round 4
// 133.028 us; speedup vs baseline: 2.8838x; 1.1192x over previous
//
#include <hip/hip_runtime.h>

#define B_TOK 2048
#define W_DIM 512
#define E_N 16
#define INTER 1024
#define SH_INTER 2048
#define OUT_DIM 128

typedef unsigned short u16;
typedef unsigned int u32;
typedef __attribute__((ext_vector_type(8))) short bf16x8;
typedef __attribute__((ext_vector_type(4))) float f32x4;

__device__ __forceinline__ u16 f2b(float f) {
    union { float f; unsigned u; } x; x.f = f;
    unsigned r = x.u + 0x7FFFu + ((x.u >> 16) & 1u);
    return (u16)(r >> 16);
}

__device__ __forceinline__ u32 cvtpk(float lo, float hi) {
    u32 r;
    asm("v_cvt_pk_bf16_f32 %0, %1, %2" : "=v"(r) : "v"(lo), "v"(hi));
    return r;
}

__device__ __forceinline__ void gld16(const void* g, void* l) {
    __builtin_amdgcn_global_load_lds(
        (const __attribute__((address_space(1))) void*)g,
        (__attribute__((address_space(3))) void*)l, 16, 0, 0);
}

// meta layout (ints):
// [0..15] counts  [32..47] offs
// [50] n_j1  [51] n_j2
// [64..127] j1e  [128..191] j1m   (g1 jobs, BM=128)
// [192..303] j2e [304..415] j2m   (g2 jobs, BM=64)

// ---------------- fused cast fp32->bf16 over 8 segments (8 elems/thread/iter) ----
struct CastSeg { const float4* src; uint4* dst; int n8; };
struct CastArgs { CastSeg s[8]; int total8; };

__global__ __launch_bounds__(256)
void cast_all(CastArgs a) {
    for (int i = blockIdx.x * 256 + threadIdx.x; i < a.total8; i += gridDim.x * 256) {
        int r = i, s = 0;
        while (r >= a.s[s].n8) { r -= a.s[s].n8; ++s; }
        float4 v0 = a.s[s].src[r * 2];
        float4 v1 = a.s[s].src[r * 2 + 1];
        uint4 o;
        o.x = cvtpk(v0.x, v0.y);
        o.y = cvtpk(v0.z, v0.w);
        o.z = cvtpk(v1.x, v1.y);
        o.w = cvtpk(v1.z, v1.w);
        a.s[s].dst[r] = o;
    }
}

// ---------------- gate: fp32 logits, softmax, top-2 (NO atomics) ----------------
__global__ __launch_bounds__(256)
void gate_topk(const float* __restrict__ x, const float* __restrict__ gw,
               int* __restrict__ topi, float* __restrict__ topw) {
    const int lane = threadIdx.x & 63;
    const int wv   = threadIdx.x >> 6;
    const int t    = blockIdx.x * 4 + wv;
    const int e = lane >> 2, q = lane & 3;
    const float4* xr = (const float4*)(x + (size_t)t * W_DIM);
    const float4* wr = (const float4*)(gw + (size_t)e * W_DIM);
    float s = 0.f;
    #pragma unroll
    for (int i = 0; i < W_DIM / 16; ++i) {
        float4 a = xr[q + 4 * i];
        float4 b = wr[q + 4 * i];
        s += a.x * b.x + a.y * b.y + a.z * b.z + a.w * b.w;
    }
    s += __shfl_xor(s, 1);
    s += __shfl_xor(s, 2);
    float sc[16];
    #pragma unroll
    for (int ee = 0; ee < 16; ++ee) sc[ee] = __shfl(s, ee * 4);
    float mx = sc[0];
    #pragma unroll
    for (int ee = 1; ee < 16; ++ee) mx = fmaxf(mx, sc[ee]);
    float p[16]; float sum = 0.f;
    #pragma unroll
    for (int ee = 0; ee < 16; ++ee) { p[ee] = expf(sc[ee] - mx); sum += p[ee]; }
    const float inv = 1.f / sum;
    int i0 = 0; float v0 = sc[0];
    #pragma unroll
    for (int ee = 1; ee < 16; ++ee) if (sc[ee] > v0) { v0 = sc[ee]; i0 = ee; }
    int i1 = -1; float v1 = -1e30f;
    #pragma unroll
    for (int ee = 0; ee < 16; ++ee) if (ee != i0 && sc[ee] > v1) { v1 = sc[ee]; i1 = ee; }
    if (lane == 0) {
        topi[t * 2 + 0] = i0; topi[t * 2 + 1] = i1;
        topw[t * 2 + 0] = p[i0] * inv; topw[t * 2 + 1] = p[i1] * inv;
    }
}

// ---------------- route_build: single block, LDS atomics only ----------------
__global__ __launch_bounds__(256)
void route_build(const int* __restrict__ topi, const float* __restrict__ topw,
                 int* __restrict__ meta, int* __restrict__ glist,
                 float* __restrict__ job_w, int* __restrict__ t2r) {
    __shared__ int cnt[16], cur[16], offs[16];
    const int tid = threadIdx.x;
    if (tid < 16) { cnt[tid] = 0; cur[tid] = 0; }
    __syncthreads();
    for (int i = tid; i < 2 * B_TOK; i += 256) atomicAdd(&cnt[topi[i]], 1);
    __syncthreads();
    if (tid == 0) {
        int acc = 0, jc = 0;
        for (int e = 0; e < 16; ++e) {
            offs[e] = acc; meta[e] = cnt[e]; meta[32 + e] = acc; acc += cnt[e];
        }
        for (int e = 0; e < 16; ++e)
            for (int m = 0; m < cnt[e]; m += 128) { meta[64 + jc] = e; meta[128 + jc] = m; ++jc; }
        for (int m = 0; m < B_TOK; m += 128) { meta[64 + jc] = 16; meta[128 + jc] = m; ++jc; }
        meta[50] = jc;
        jc = 0;
        for (int e = 0; e < 16; ++e)
            for (int m = 0; m < cnt[e]; m += 64) { meta[192 + jc] = e; meta[304 + jc] = m; ++jc; }
        for (int m = 0; m < B_TOK; m += 64) { meta[192 + jc] = 16; meta[304 + jc] = m; ++jc; }
        meta[51] = jc;
    }
    __syncthreads();
    for (int i = tid; i < 2 * B_TOK; i += 256) {
        int e = topi[i];
        int pos = atomicAdd(&cur[e], 1);
        int row = offs[e] + pos;
        glist[row] = i >> 1;
        job_w[row] = topw[i];
        t2r[i] = row;
    }
    for (int t = tid; t < B_TOK; t += 256) glist[4096 + t] = t;
}

// ---------------- G1 merged: dual GEMM + leaky*mul, bf16 gld16, 2-phase dbuf ----
// BM=128 BN=64 BK=32; stage = A 4096 u16 + B1 2048 + B3 2048 = 8192 u16 (16KB), x2
__global__ __launch_bounds__(256)
void g1_dual(const u16* __restrict__ xb, const int* __restrict__ glist, const int* __restrict__ meta,
             const u16* __restrict__ w1b, const u16* __restrict__ w3b,
             const float* __restrict__ b1, const float* __restrict__ b3,
             const u16* __restrict__ sw1b, const u16* __restrict__ sw3b,
             const float* __restrict__ sb1, const float* __restrict__ sb3,
             u16* __restrict__ hbuf, u16* __restrict__ pbuf) {
    const int job = blockIdx.x;
    if (job >= meta[50]) return;
    const int e  = meta[64 + job];
    const int m0 = meta[128 + job];
    const bool sh = (e == 16);
    if (!sh && blockIdx.y >= (INTER / 64)) return;
    const int n0 = blockIdx.y * 64;
    const int N  = sh ? SH_INTER : INTER;
    const u16* B1 = sh ? sw1b : (w1b + (size_t)e * INTER * W_DIM);
    const u16* B3 = sh ? sw3b : (w3b + (size_t)e * INTER * W_DIM);
    const float* bb1 = sh ? sb1 : (b1 + (size_t)e * INTER);
    const float* bb3 = sh ? sb3 : (b3 + (size_t)e * INTER);
    const int abase = sh ? (4096 + m0) : (meta[32 + e] + m0);
    const int Mrows = (sh ? B_TOK : meta[e]) - m0;
    u16* outp = sh ? pbuf : hbuf;
    const int orow0 = sh ? m0 : (meta[32 + e] + m0);

    __shared__ __align__(16) u16 lds[2 * 8192];

    const int tid = threadIdx.x, lane = tid & 63, wv = tid >> 6;
    const int rA0 = tid >> 2, rA1 = rA0 + 64;
    const int kq = (tid & 3) * 8;
    const int tok0 = glist[abase + (rA0 < Mrows ? rA0 : Mrows - 1)];
    const int tok1 = glist[abase + (rA1 < Mrows ? rA1 : Mrows - 1)];
    const u16* gA0 = xb + (size_t)tok0 * W_DIM + kq;
    const u16* gA1 = xb + (size_t)tok1 * W_DIM + kq;
    const u16* gB1 = B1 + (size_t)(n0 + rA0) * W_DIM + kq;
    const u16* gB3 = B3 + (size_t)(n0 + rA0) * W_DIM + kq;

    const int wm = wv >> 1, wn = wv & 1;
    const int l15 = lane & 15, lhi = lane >> 4;

    f32x4 a1[4][2] = {};
    f32x4 a3[4][2] = {};

    auto stage = [&](int s, int k0) {
        u16* b = &lds[s * 8192];
        gld16(gA0 + k0, b + tid * 8);
        gld16(gA1 + k0, b + 2048 + tid * 8);
        gld16(gB1 + k0, b + 4096 + tid * 8);
        gld16(gB3 + k0, b + 6144 + tid * 8);
    };

    const int NT = W_DIM / 32;
    int cur = 0;
    stage(0, 0);
    for (int t = 0; t < NT; ++t) {
        __syncthreads();
        if (t + 1 < NT) stage(cur ^ 1, (t + 1) * 32);
        const u16* bb = &lds[cur * 8192];
        bf16x8 af[4], f1[2], f3[2];
        #pragma unroll
        for (int i = 0; i < 4; ++i)
            af[i] = *(const bf16x8*)&bb[(wm * 64 + i * 16 + l15) * 32 + lhi * 8];
        #pragma unroll
        for (int j = 0; j < 2; ++j) {
            f1[j] = *(const bf16x8*)&bb[4096 + (wn * 32 + j * 16 + l15) * 32 + lhi * 8];
            f3[j] = *(const bf16x8*)&bb[6144 + (wn * 32 + j * 16 + l15) * 32 + lhi * 8];
        }
        #pragma unroll
        for (int i = 0; i < 4; ++i)
            #pragma unroll
            for (int j = 0; j < 2; ++j) {
                a1[i][j] = __builtin_amdgcn_mfma_f32_16x16x32_bf16(af[i], f1[j], a1[i][j], 0, 0, 0);
                a3[i][j] = __builtin_amdgcn_mfma_f32_16x16x32_bf16(af[i], f3[j], a3[i][j], 0, 0, 0);
            }
        cur ^= 1;
    }

    #pragma unroll
    for (int i = 0; i < 4; ++i)
    #pragma unroll
    for (int j = 0; j < 2; ++j) {
        const int col = n0 + wn * 32 + j * 16 + l15;
        const float vb1 = bb1[col];
        const float vb3 = bb3[col];
        #pragma unroll
        for (int r = 0; r < 4; ++r) {
            const int gm = wm * 64 + i * 16 + lhi * 4 + r;
            if (gm < Mrows) {
                float v1 = a1[i][j][r] + vb1;
                float v3 = a3[i][j][r] + vb3;
                v1 = v1 >= 0.f ? v1 : 0.01f * v1;
                outp[(size_t)(orow0 + gm) * N + col] = f2b(v1 * v3);
            }
        }
    }
}

// ---------------- G2 merged: GEMM + bias (+scale), bf16 gld16, fp32 out ----------
// BM=64 BN=64 BK=32; stage = 2048 + 2048 u16 (8KB), x2
__global__ __launch_bounds__(256)
void g2_gemm(const int* __restrict__ meta,
             const u16* __restrict__ hbuf, const u16* __restrict__ pbuf,
             const u16* __restrict__ w2b, const float* __restrict__ b2,
             const u16* __restrict__ sw2b, const float* __restrict__ sb2,
             const float* __restrict__ job_w,
             float* __restrict__ y2, float* __restrict__ zbuf) {
    const int job = blockIdx.x;
    if (job >= meta[51]) return;
    const int e  = meta[192 + job];
    const int m0 = meta[304 + job];
    const bool sh = (e == 16);
    const int n0 = blockIdx.y * 64;
    const int K  = sh ? SH_INTER : INTER;
    const u16* A = sh ? pbuf : hbuf;
    const int Arow0 = sh ? m0 : (meta[32 + e] + m0);
    const u16* Bw = sh ? sw2b : (w2b + (size_t)e * W_DIM * INTER);
    const float* bias = sh ? sb2 : (b2 + (size_t)e * W_DIM);
    const int Mrows = (sh ? B_TOK : meta[e]) - m0;
    const float* scale = sh ? nullptr : (job_w + Arow0);
    float* outp = sh ? zbuf : y2;

    __shared__ __align__(16) u16 lds[2 * 4096];

    const int tid = threadIdx.x, lane = tid & 63, wv = tid >> 6;
    const int rA = tid >> 2;
    const int kq = (tid & 3) * 8;
    const u16* gA = A + (size_t)(Arow0 + (rA < Mrows ? rA : Mrows - 1)) * K + kq;
    const u16* gB = Bw + (size_t)(n0 + rA) * K + kq;

    const int wm = wv >> 1, wn = wv & 1;
    const int l15 = lane & 15, lhi = lane >> 4;

    f32x4 acc[2][2] = {};

    auto stage = [&](int s, int k0) {
        u16* b = &lds[s * 4096];
        gld16(gA + k0, b + tid * 8);
        gld16(gB + k0, b + 2048 + tid * 8);
    };

    const int NT = K / 32;
    int cur = 0;
    stage(0, 0);
    for (int t = 0; t < NT; ++t) {
        __syncthreads();
        if (t + 1 < NT) stage(cur ^ 1, (t + 1) * 32);
        const u16* bb = &lds[cur * 4096];
        bf16x8 af[2], bf[2];
        #pragma unroll
        for (int i = 0; i < 2; ++i)
            af[i] = *(const bf16x8*)&bb[(wm * 32 + i * 16 + l15) * 32 + lhi * 8];
        #pragma unroll
        for (int j = 0; j < 2; ++j)
            bf[j] = *(const bf16x8*)&bb[2048 + (wn * 32 + j * 16 + l15) * 32 + lhi * 8];
        #pragma unroll
        for (int i = 0; i < 2; ++i)
            #pragma unroll
            for (int j = 0; j < 2; ++j)
                acc[i][j] = __builtin_amdgcn_mfma_f32_16x16x32_bf16(af[i], bf[j], acc[i][j], 0, 0, 0);
        cur ^= 1;
    }

    #pragma unroll
    for (int i = 0; i < 2; ++i)
    #pragma unroll
    for (int j = 0; j < 2; ++j) {
        const int col = n0 + wn * 32 + j * 16 + l15;
        const float bb = bias[col];
        #pragma unroll
        for (int r = 0; r < 4; ++r) {
            const int gm = wm * 32 + i * 16 + lhi * 4 + r;
            if (gm < Mrows) {
                float v = acc[i][j][r] + bb;
                if (scale) v *= scale[gm];
                outp[(size_t)(Arow0 + gm) * W_DIM + col] = v;
            }
        }
    }
}

// ---------------- combine: ybf = bf16(y2[r0] + y2[r1] + z) ----------------
__global__ __launch_bounds__(256)
void combine_k(const float* __restrict__ y2, const float* __restrict__ z,
               const int* __restrict__ t2r, u16* __restrict__ ybf) {
    int idx = blockIdx.x * 256 + threadIdx.x;
    int t = idx >> 7;
    int w4 = (idx & 127) << 2;
    int r0 = t2r[t * 2 + 0], r1 = t2r[t * 2 + 1];
    const float4 a = *(const float4*)(y2 + (size_t)r0 * W_DIM + w4);
    const float4 b = *(const float4*)(y2 + (size_t)r1 * W_DIM + w4);
    const float4 c = *(const float4*)(z + (size_t)t * W_DIM + w4);
    ushort4 o;
    o.x = f2b(a.x + b.x + c.x);
    o.y = f2b(a.y + b.y + c.y);
    o.z = f2b(a.z + b.z + c.z);
    o.w = f2b(a.w + b.w + c.w);
    *(ushort4*)(ybf + (size_t)t * W_DIM + w4) = o;
}

// ---------------- output projection: out = ybf @ ow^T + ob ----------------
__global__ __launch_bounds__(256)
void gout(const u16* __restrict__ ybf, const u16* __restrict__ owb,
          const float* __restrict__ ob, float* __restrict__ out) {
    const int m0 = blockIdx.x * 64, n0 = blockIdx.y * 64;
    __shared__ __align__(16) u16 lds[2 * 4096];
    const int tid = threadIdx.x, lane = tid & 63, wv = tid >> 6;
    const int rA = tid >> 2;
    const int kq = (tid & 3) * 8;
    const u16* gA = ybf + (size_t)(m0 + rA) * W_DIM + kq;
    const u16* gB = owb + (size_t)(n0 + rA) * W_DIM + kq;
    const int wm = wv >> 1, wn = wv & 1;
    const int l15 = lane & 15, lhi = lane >> 4;
    f32x4 acc[2][2] = {};
    auto stage = [&](int s, int k0) {
        u16* b = &lds[s * 4096];
        gld16(gA + k0, b + tid * 8);
        gld16(gB + k0, b + 2048 + tid * 8);
    };
    const int NT = W_DIM / 32;
    int cur = 0;
    stage(0, 0);
    for (int t = 0; t < NT; ++t) {
        __syncthreads();
        if (t + 1 < NT) stage(cur ^ 1, (t + 1) * 32);
        const u16* bb = &lds[cur * 4096];
        bf16x8 af[2], bf[2];
        #pragma unroll
        for (int i = 0; i < 2; ++i)
            af[i] = *(const bf16x8*)&bb[(wm * 32 + i * 16 + l15) * 32 + lhi * 8];
        #pragma unroll
        for (int j = 0; j < 2; ++j)
            bf[j] = *(const bf16x8*)&bb[2048 + (wn * 32 + j * 16 + l15) * 32 + lhi * 8];
        #pragma unroll
        for (int i = 0; i < 2; ++i)
            #pragma unroll
            for (int j = 0; j < 2; ++j)
                acc[i][j] = __builtin_amdgcn_mfma_f32_16x16x32_bf16(af[i], bf[j], acc[i][j], 0, 0, 0);
        cur ^= 1;
    }
    #pragma unroll
    for (int i = 0; i < 2; ++i)
    #pragma unroll
    for (int j = 0; j < 2; ++j) {
        const int col = n0 + wn * 32 + j * 16 + l15;
        if (col < OUT_DIM) {
            const float bb = ob[col];
            #pragma unroll
            for (int r = 0; r < 4; ++r) {
                const int gm = wm * 32 + i * 16 + lhi * 4 + r;
                out[(size_t)(m0 + gm) * OUT_DIM + col] = acc[i][j][r] + bb;
            }
        }
    }
}

extern "C" void kernel_launch(void* const* d_in, const int* in_sizes, int n_in,
                              void* d_out, int out_size, void* d_ws, size_t ws_size,
                              hipStream_t stream) {
    const float* x      = (const float*)d_in[0];
    const float* gate_w = (const float*)d_in[2];
    const float* w1     = (const float*)d_in[3];
    const float* b1     = (const float*)d_in[4];
    const float* w2     = (const float*)d_in[5];
    const float* b2     = (const float*)d_in[6];
    const float* w3     = (const float*)d_in[7];
    const float* b3     = (const float*)d_in[8];
    const float* sw1    = (const float*)d_in[9];
    const float* sb1    = (const float*)d_in[10];
    const float* sw2    = (const float*)d_in[11];
    const float* sb2    = (const float*)d_in[12];
    const float* sw3    = (const float*)d_in[13];
    const float* sb3    = (const float*)d_in[14];
    const float* ow     = (const float*)d_in[15];
    const float* ob     = (const float*)d_in[16];
    float* out = (float*)d_out;

    char* ws = (char*)d_ws;
    size_t off = 0;
    auto alloc = [&](size_t bytes) -> void* {
        void* p = (void*)(ws + off);
        off += (bytes + 255) & ~(size_t)255;
        return p;
    };

    int*   meta   = (int*)alloc(2048);
    int*   topi   = (int*)alloc((size_t)B_TOK * 2 * 4);
    float* topw   = (float*)alloc((size_t)B_TOK * 2 * 4);
    int*   t2r    = (int*)alloc((size_t)B_TOK * 2 * 4);
    int*   glist  = (int*)alloc((size_t)(B_TOK * 2 + B_TOK) * 4);
    float* job_w  = (float*)alloc((size_t)B_TOK * 2 * 4);
    u16*   xb     = (u16*)alloc((size_t)B_TOK * W_DIM * 2);
    u16*   w1b    = (u16*)alloc((size_t)E_N * INTER * W_DIM * 2);
    u16*   w3b    = (u16*)alloc((size_t)E_N * INTER * W_DIM * 2);
    u16*   w2b    = (u16*)alloc((size_t)E_N * W_DIM * INTER * 2);
    u16*   sw1b   = (u16*)alloc((size_t)SH_INTER * W_DIM * 2);
    u16*   sw3b   = (u16*)alloc((size_t)SH_INTER * W_DIM * 2);
    u16*   sw2b   = (u16*)alloc((size_t)W_DIM * SH_INTER * 2);
    u16*   owb    = (u16*)alloc((size_t)OUT_DIM * W_DIM * 2);
    u16*   hbuf   = (u16*)alloc((size_t)B_TOK * 2 * INTER * 2);
    u16*   pbuf   = (u16*)alloc((size_t)B_TOK * SH_INTER * 2);
    float* y2     = (float*)alloc((size_t)B_TOK * 2 * W_DIM * 4);
    float* zbuf   = (float*)alloc((size_t)B_TOK * W_DIM * 4);
    u16*   ybf    = (u16*)alloc((size_t)B_TOK * W_DIM * 2);
    if (off > ws_size) return;

    dim3 blk(256);

    CastArgs ca;
    ca.s[0] = { (const float4*)x,   (uint4*)xb,   B_TOK * W_DIM / 8 };
    ca.s[1] = { (const float4*)w1,  (uint4*)w1b,  E_N * INTER * W_DIM / 8 };
    ca.s[2] = { (const float4*)w3,  (uint4*)w3b,  E_N * INTER * W_DIM / 8 };
    ca.s[3] = { (const float4*)w2,  (uint4*)w2b,  E_N * W_DIM * INTER / 8 };
    ca.s[4] = { (const float4*)sw1, (uint4*)sw1b, SH_INTER * W_DIM / 8 };
    ca.s[5] = { (const float4*)sw3, (uint4*)sw3b, SH_INTER * W_DIM / 8 };
    ca.s[6] = { (const float4*)sw2, (uint4*)sw2b, W_DIM * SH_INTER / 8 };
    ca.s[7] = { (const float4*)ow,  (uint4*)owb,  OUT_DIM * W_DIM / 8 };
    ca.total8 = 0;
    for (int i = 0; i < 8; ++i) ca.total8 += ca.s[i].n8;
    cast_all<<<dim3(2048), blk, 0, stream>>>(ca);

    gate_topk<<<dim3(B_TOK / 4), blk, 0, stream>>>(x, gate_w, topi, topw);
    route_build<<<1, blk, 0, stream>>>(topi, topw, meta, glist, job_w, t2r);

    // g1 merged: routed (<=48 jobs) + shared (16 jobs)
    g1_dual<<<dim3(64, SH_INTER / 64), blk, 0, stream>>>(
        xb, glist, meta, w1b, w3b, b1, b3, sw1b, sw3b, sb1, sb3, hbuf, pbuf);

    // g2 merged: routed (<=80 jobs) + shared (32 jobs)
    g2_gemm<<<dim3(112, W_DIM / 64), blk, 0, stream>>>(
        meta, hbuf, pbuf, w2b, b2, sw2b, sb2, job_w, y2, zbuf);

    combine_k<<<dim3(B_TOK * W_DIM / 4 / 256), blk, 0, stream>>>(y2, zbuf, t2r, ybf);

    gout<<<dim3(B_TOK / 64, 2), blk, 0, stream>>>(ybf, owb, ob, out);
}